// Round 4
// baseline (247.571 us; speedup 1.0000x reference)
//
#include <hip/hip_runtime.h>
#include <hip/hip_bf16.h>

typedef unsigned short u16;
typedef unsigned char u8;
typedef float f32x4 __attribute__((ext_vector_type(4)));
typedef int int4v __attribute__((ext_vector_type(4)));
typedef int int8v __attribute__((ext_vector_type(8)));

#define B_ROWS 8192
#define D_DIM  1024
#define FP8_SCALE 16.0f          // store x*16 in e4m3; acc = 256 * s_true
#define ACC_UNSCALE (1.0f/256.0f)

// ---------------------------------------------------------------------------
// Workspace layout (bytes):
//   [0,      32768)   ppq[8192]   per-row MSE(q) partial
//   [32768,  65536)   ppp[8192]   per-row MSE(p) partial
//   [65536,  98304)   ppd[8192]   per-row diag cosine (exact fp32)
//   [98304,  98816)   bpart[32][4] per-reduce-block partials
//   [131072, +4MiB)   gpart[128][8192]  per-64-col-slice row exp-sum partials
//   [+4MiB,  +8MiB)   qn fp8 [8192][1024]   (x16 pre-scaled e4m3)
//   [+8MiB,  ...)     pn fp8 [8192][1024]
// ---------------------------------------------------------------------------

// ---------------------------------------------------------------------------
// Kernel 1: one WAVE per row — butterfly reduce, fp8 quantize. (unchanged)
// ---------------------------------------------------------------------------
__global__ void __launch_bounds__(256) prep_kernel(
    const float* __restrict__ sq, const float* __restrict__ sp,
    const float* __restrict__ tq, const float* __restrict__ tp,
    int* __restrict__ qn, int* __restrict__ pn,
    float* __restrict__ ppq, float* __restrict__ ppp, float* __restrict__ ppd)
{
    const int wave = threadIdx.x >> 6;
    const int l    = threadIdx.x & 63;
    const int r    = blockIdx.x * 4 + wave;
    const size_t rb4 = (size_t)r * (D_DIM / 4);

    const float4* Q4 = (const float4*)sq + rb4;
    const float4* P4 = (const float4*)sp + rb4;
    const float4* A4 = (const float4*)tq + rb4;
    const float4* B4 = (const float4*)tp + rb4;

    float4 qv[4], pv[4];
    float sq2 = 0.f, sp2 = 0.f, dq = 0.f, dp = 0.f, qp = 0.f;
    #pragma unroll
    for (int j = 0; j < 4; ++j) {
        const int idx = j * 64 + l;
        float4 q = Q4[idx], p = P4[idx], a = A4[idx], b = B4[idx];
        qv[j] = q; pv[j] = p;
        sq2 += q.x*q.x + q.y*q.y + q.z*q.z + q.w*q.w;
        sp2 += p.x*p.x + p.y*p.y + p.z*p.z + p.w*p.w;
        float dx = q.x-a.x, dy = q.y-a.y, dz = q.z-a.z, dw = q.w-a.w;
        dq += dx*dx + dy*dy + dz*dz + dw*dw;
        dx = p.x-b.x; dy = p.y-b.y; dz = p.z-b.z; dw = p.w-b.w;
        dp += dx*dx + dy*dy + dz*dz + dw*dw;
        qp += q.x*p.x + q.y*p.y + q.z*p.z + q.w*p.w;
    }

    #pragma unroll
    for (int m = 1; m <= 32; m <<= 1) {
        sq2 += __shfl_xor(sq2, m);
        sp2 += __shfl_xor(sp2, m);
        dq  += __shfl_xor(dq, m);
        dp  += __shfl_xor(dp, m);
        qp  += __shfl_xor(qp, m);
    }

    const float rq = 1.0f / fmaxf(sqrtf(sq2), 1e-8f);
    const float rp = 1.0f / fmaxf(sqrtf(sp2), 1e-8f);

    if (l == 0) {
        ppq[r] = dq;
        ppp[r] = dp;
        ppd[r] = qp * rq * rp;
    }

    const float fq = rq * FP8_SCALE;
    const float fp = rp * FP8_SCALE;
    int* qrow = qn + (size_t)r * (D_DIM / 4);
    int* prow = pn + (size_t)r * (D_DIM / 4);
    #pragma unroll
    for (int j = 0; j < 4; ++j) {
        const int idx = j * 64 + l;
        int pk = __builtin_amdgcn_cvt_pk_fp8_f32(qv[j].x * fq, qv[j].y * fq, 0, false);
        pk     = __builtin_amdgcn_cvt_pk_fp8_f32(qv[j].z * fq, qv[j].w * fq, pk, true);
        qrow[idx] = pk;
        pk = __builtin_amdgcn_cvt_pk_fp8_f32(pv[j].x * fp, pv[j].y * fp, 0, false);
        pk = __builtin_amdgcn_cvt_pk_fp8_f32(pv[j].z * fp, pv[j].w * fp, pk, true);
        prow[idx] = pk;
    }
}

// ---------------------------------------------------------------------------
// Kernel 2: S = Qn @ Pn^T via MX-scaled fp8 MFMA 16x16x128, 256x256 tile,
// 8 waves (2M x 4N).  A-only LDS (64 KiB double-buffered); B read DIRECT
// from global/L2 into registers each K-step (lane-local fragment layout:
// lane l = B-row l&15, k-bytes 32*(l>>4)..+32 -> 2 dwordx4 per fragment).
//
//  per K-step t (buf c = t&1):
//   - load b[0..3] (8 global_load_dwordx4, L2-resident panel)
//   - vmcnt(12) counted (retires A(t); leaves B(t)+A(t+1) in flight); BARRIER
//   - ds_read af0-7 (16 b128, XOR-swizzled); lgkm(0); BARRIER (restage-safe)
//   - MFMA af0-3 x b0-3 (16)   [compiler inserts the b-dep vmcnt here;
//                               B had the whole ds_read window to land]
//   - stage A(t+2)->buf[c] (4 global_load_lds, counted across steps)
//   - MFMA af4-7 x b0-3 (16)
//
//  vs the previous all-LDS version: DS reads/step 192->128 per CU, staging
//  writes halved, B traffic moved to the idle vmem/L2 pipe.  Grid is 1D
//  with a bijective XCD-chunked decode so each XCD's 4 B-panels (1 MiB)
//  stay L2-resident.  Numerics bit-identical (same fragment bytes, same
//  per-acc MFMA chain order).
// ---------------------------------------------------------------------------
union Frag { int8v v8; struct { int4v lo, hi; } h; };

__global__ void __launch_bounds__(512, 2) gemm_rowsum_kernel(
    const u8* __restrict__ Q, const u8* __restrict__ P,
    float* __restrict__ gpart)
{
    __shared__ u8 smA[2][256 * 128];   // 2 x 32 KiB, row stride 128 B (A only)

    const int tid  = threadIdx.x;
    const int wave = tid >> 6;
    const int lane = tid & 63;
    const int wm   = wave >> 2;        // 0..1 : row half of the 256-row tile
    const int wn   = wave & 3;         // 0..3 : 64-col quarter

    // XCD-chunked bijective decode: 1024 blocks, 8 XCDs, 4 bn-columns/XCD.
    const int bid = blockIdx.x;
    const int xcd = bid & 7;
    const int idx = bid >> 3;          // 0..127
    const int bn  = (xcd << 2) | (idx & 3);   // 0..31, chunked per XCD
    const int bm  = idx >> 2;                 // 0..31

    // A staging: one global_load_lds per thread covers 64 rows x 128 B.
    // LDS written linearly; 16B-chunk XOR swizzle applied on the GLOBAL
    // source address (pre-swizzle), read side XORs with row&7.
    const int srow   = tid >> 3;                    // 0..63 within chunk
    const int schunk = (tid & 7) ^ (srow & 7);      // pre-swizzled 16B chunk
    const u8* Ag = Q + (size_t)(bm * 256 + srow) * D_DIM + schunk * 16;
    const int ldsw = wave * 1024;                   // wave's 8-row sub-chunk

#define STAGE_A(b, rbase, k0)                                                  \
    __builtin_amdgcn_global_load_lds(                                          \
        (const __attribute__((address_space(1))) void*)(Ag + (size_t)(rbase) * D_DIM + (k0)), \
        (__attribute__((address_space(3))) void*)(&smA[b][(rbase) * 128] + ldsw), 16, 0, 0)

    // fragment addressing:
    // A frag (mi): row = wm*128 + mi*16 + rw, k-chunks 2q,2q+1 (XOR row&7)
    const int quad = lane >> 4;
    const int rw   = lane & 15;
    const int r7   = lane & 7;
    const int off_lo = ((2 * quad) ^ r7) * 16;
    const int off_hi = ((2 * quad + 1) ^ r7) * 16;
    const int arow_base = (wm * 128 + rw) * 128;    // + mi*2048

    // B direct-load base: lane l covers B-row (bn*256 + wn*64 + ni*16 + rw),
    // k-bytes (l>>4)*32 .. +32 of k-chunk t*128.
    const u8* Bd = P + (size_t)(bn * 256 + wn * 64 + rw) * D_DIM + quad * 32;

    f32x4 acc[8][4];
    #pragma unroll
    for (int i = 0; i < 8; ++i)
        #pragma unroll
        for (int j = 0; j < 4; ++j)
            acc[i][j] = (f32x4){0.f, 0.f, 0.f, 0.f};

    // prologue: stage A(0)->buf0, A(1)->buf1 (8 loads)
    STAGE_A(0, 0, 0);   STAGE_A(0, 64, 0);   STAGE_A(0, 128, 0);   STAGE_A(0, 192, 0);
    STAGE_A(1, 0, 128); STAGE_A(1, 64, 128); STAGE_A(1, 128, 128); STAGE_A(1, 192, 128);

#define SB0 __builtin_amdgcn_sched_barrier(0);

#define MFMA_HALF(mih)                                                         \
    __builtin_amdgcn_s_setprio(1);                                             \
    _Pragma("unroll")                                                          \
    for (int mi = 0; mi < 4; ++mi)                                             \
      _Pragma("unroll")                                                        \
      for (int ni = 0; ni < 4; ++ni)                                           \
        acc[(mih)*4 + mi][ni] =                                                \
            __builtin_amdgcn_mfma_scale_f32_16x16x128_f8f6f4(                  \
                af[(mih)*4 + mi].v8, b[ni].v8,                                 \
                acc[(mih)*4 + mi][ni],                                         \
                0, 0, 0, 0x7f7f7f7f, 0, 0x7f7f7f7f);                           \
    __builtin_amdgcn_s_setprio(0);

#define KSTEP(t, DO_T2)                                                        \
  {                                                                            \
    constexpr int cur = (t) & 1;                                               \
    const u8* sA_ = &smA[cur][0];                                              \
    Frag af[8], b[4];                                                          \
    /* B(t) direct from L2 into regs (lane-local fragment layout) */           \
    _Pragma("unroll")                                                          \
    for (int ni = 0; ni < 4; ++ni) {                                           \
      b[ni].h.lo = *(const int4v*)(Bd + ni * 16 * D_DIM + (t) * 128);          \
      b[ni].h.hi = *(const int4v*)(Bd + ni * 16 * D_DIM + (t) * 128 + 16);     \
    }                                                                          \
    /* counted A fence: newest 12 = B(t):8 + A(t+1):4 stay in flight */        \
    asm volatile("s_waitcnt vmcnt(12)" ::: "memory");                          \
    __builtin_amdgcn_s_barrier();                                              \
    SB0                                                                        \
    /* af0-7 reads (all lo group, then all hi group) = 16 b128 */              \
    _Pragma("unroll")                                                          \
    for (int mi = 0; mi < 8; ++mi)                                             \
      af[mi].h.lo = *(const int4v*)(sA_ + arow_base + mi * 2048 + off_lo);     \
    SB0                                                                        \
    _Pragma("unroll")                                                          \
    for (int mi = 0; mi < 8; ++mi)                                             \
      af[mi].h.hi = *(const int4v*)(sA_ + arow_base + mi * 2048 + off_hi);     \
    asm volatile("s_waitcnt lgkmcnt(0)" ::: "memory");                         \
    SB0                                                                        \
    __builtin_amdgcn_s_barrier();   /* all waves done reading buf[cur] */      \
    MFMA_HALF(0)                                                               \
    if (DO_T2) { STAGE_A(cur, 0,   ((t) + 2) * 128);                           \
                 STAGE_A(cur, 64,  ((t) + 2) * 128);                           \
                 STAGE_A(cur, 128, ((t) + 2) * 128);                           \
                 STAGE_A(cur, 192, ((t) + 2) * 128); }                         \
    MFMA_HALF(1)                                                               \
  }

    KSTEP(0, true)
    KSTEP(1, true)
    KSTEP(2, true)
    KSTEP(3, true)
    KSTEP(4, true)
    KSTEP(5, true)
    KSTEP(6, false)
    KSTEP(7, false)

#undef KSTEP
#undef MFMA_HALF
#undef SB0
#undef STAGE_A

    // epilogue: per-row sum of exp over this wave's 64 columns.
    // C/D layout (shape-determined): col = lane&15, row = quad*4 + reg
    float esum[8][4];
    #pragma unroll
    for (int mi = 0; mi < 8; ++mi)
        #pragma unroll
        for (int r = 0; r < 4; ++r) {
            float s = 0.f;
            #pragma unroll
            for (int ni = 0; ni < 4; ++ni)
                s += __expf(acc[mi][ni][r] * ACC_UNSCALE);
            esum[mi][r] = s;
        }
    #pragma unroll
    for (int m = 1; m <= 8; m <<= 1)
        #pragma unroll
        for (int mi = 0; mi < 8; ++mi)
            #pragma unroll
            for (int r = 0; r < 4; ++r)
                esum[mi][r] += __shfl_xor(esum[mi][r], m);

    // slice index = global_col / 64 = bn*4 + wn
    if (rw == 0) {
        float* dst = gpart + (size_t)(bn * 4 + wn) * B_ROWS
                   + bm * 256 + wm * 128;
        #pragma unroll
        for (int mi = 0; mi < 8; ++mi)
            #pragma unroll
            for (int r = 0; r < 4; ++r)
                dst[mi * 16 + quad * 4 + r] = esum[mi][r];
    }
}

// ---------------------------------------------------------------------------
// Kernel 3: per-row sum of 128 gpart slices -> log; fold in the three
// pp-array reductions; one float4 partial per block. (unchanged)
// ---------------------------------------------------------------------------
__global__ void __launch_bounds__(256) reduce_kernel(
    const float* __restrict__ gpart,
    const float* __restrict__ ppq, const float* __restrict__ ppp,
    const float* __restrict__ ppd, float4* __restrict__ bpart)
{
    const int t = threadIdx.x;
    const int r = blockIdx.x * 256 + t;
    float s = 0.f;
    #pragma unroll 8
    for (int j = 0; j < 128; ++j) s += gpart[(size_t)j * B_ROWS + r];
    float ls = logf(s);
    float v2 = ppq[r], v3 = ppp[r], v4 = ppd[r];
    #pragma unroll
    for (int m = 1; m <= 32; m <<= 1) {
        ls += __shfl_xor(ls, m);
        v2 += __shfl_xor(v2, m);
        v3 += __shfl_xor(v3, m);
        v4 += __shfl_xor(v4, m);
    }
    __shared__ float red[4][4];
    if ((t & 63) == 0) {
        red[t >> 6][0] = ls; red[t >> 6][1] = v2;
        red[t >> 6][2] = v3; red[t >> 6][3] = v4;
    }
    __syncthreads();
    if (t == 0) {
        float4 o;
        o.x = red[0][0] + red[1][0] + red[2][0] + red[3][0];
        o.y = red[0][1] + red[1][1] + red[2][1] + red[3][1];
        o.z = red[0][2] + red[1][2] + red[2][2] + red[3][2];
        o.w = red[0][3] + red[1][3] + red[2][3] + red[3][3];
        bpart[blockIdx.x] = o;
    }
}

// ---------------------------------------------------------------------------
// Kernel 4: final scalar combine (1 wave, 32 float4 partials) (unchanged)
// ---------------------------------------------------------------------------
__global__ void __launch_bounds__(64) finalize_kernel(
    const float4* __restrict__ bpart, float* __restrict__ out)
{
    const int t = threadIdx.x;
    float4 v = (t < 32) ? bpart[t] : (float4){0.f, 0.f, 0.f, 0.f};
    #pragma unroll
    for (int m = 1; m <= 16; m <<= 1) {
        v.x += __shfl_xor(v.x, m);
        v.y += __shfl_xor(v.y, m);
        v.z += __shfl_xor(v.z, m);
        v.w += __shfl_xor(v.w, m);
    }
    if (t == 0) {
        const float inv_bd = 1.0f / ((float)B_ROWS * (float)D_DIM);
        float distill   = 0.5f * (v.y + v.z) * inv_bd;
        float retrieval = (v.x - v.w) / (float)B_ROWS;
        out[0] = 0.5f * distill + 0.5f * retrieval;
    }
}

extern "C" void kernel_launch(void* const* d_in, const int* in_sizes, int n_in,
                              void* d_out, int out_size, void* d_ws, size_t ws_size,
                              hipStream_t stream) {
    const float* sq = (const float*)d_in[0];
    const float* sp = (const float*)d_in[1];
    const float* tq = (const float*)d_in[2];
    const float* tp = (const float*)d_in[3];

    char* ws = (char*)d_ws;
    float*  ppq   = (float*)(ws);
    float*  ppp   = (float*)(ws + 32768);
    float*  ppd   = (float*)(ws + 65536);
    float4* bpart = (float4*)(ws + 98304);
    float*  gpart = (float*)(ws + 131072);                        // 4 MiB
    int*    qn    = (int*)(ws + 131072 + (size_t)128 * B_ROWS * 4);
    int*    pn    = (int*)((char*)qn + (size_t)B_ROWS * D_DIM);

    prep_kernel<<<B_ROWS / 4, 256, 0, stream>>>(sq, sp, tq, tp, qn, pn, ppq, ppp, ppd);
    gemm_rowsum_kernel<<<1024, 512, 0, stream>>>((const u8*)qn, (const u8*)pn, gpart);
    reduce_kernel<<<32, 256, 0, stream>>>(gpart, ppq, ppp, ppd, bpart);
    finalize_kernel<<<1, 64, 0, stream>>>(bpart, (float*)d_out);
}

// Round 5
// 231.555 us; speedup vs baseline: 1.0692x; 1.0692x over previous
//
#include <hip/hip_runtime.h>
#include <hip/hip_bf16.h>

typedef unsigned short u16;
typedef unsigned char u8;
typedef float f32x4 __attribute__((ext_vector_type(4)));
typedef int int4v __attribute__((ext_vector_type(4)));
typedef int int8v __attribute__((ext_vector_type(8)));

#define B_ROWS 8192
#define D_DIM  1024
#define FP8_SCALE 16.0f          // store x*16 in e4m3; acc = 256 * s_true
#define ACC_UNSCALE (1.0f/256.0f)

// ---------------------------------------------------------------------------
// Workspace layout (bytes):
//   [0,      32768)   ppq[8192]   per-row MSE(q) partial
//   [32768,  65536)   ppp[8192]   per-row MSE(p) partial
//   [65536,  98304)   ppd[8192]   per-row diag cosine (exact fp32)
//   [98304,  98816)   bpart[32][4] per-reduce-block partials
//   [131072, +4MiB)   gpart[128][8192]  per-64-col-slice row exp-sum partials
//   [+4MiB,  +8MiB)   qn fp8 [8192][1024]   (x16 pre-scaled e4m3)
//   [+8MiB,  ...)     pn fp8 [8192][1024]
// ---------------------------------------------------------------------------

// ---------------------------------------------------------------------------
// Kernel 1: one WAVE per row — butterfly reduce, fp8 quantize. (unchanged)
// ---------------------------------------------------------------------------
__global__ void __launch_bounds__(256) prep_kernel(
    const float* __restrict__ sq, const float* __restrict__ sp,
    const float* __restrict__ tq, const float* __restrict__ tp,
    int* __restrict__ qn, int* __restrict__ pn,
    float* __restrict__ ppq, float* __restrict__ ppp, float* __restrict__ ppd)
{
    const int wave = threadIdx.x >> 6;
    const int l    = threadIdx.x & 63;
    const int r    = blockIdx.x * 4 + wave;
    const size_t rb4 = (size_t)r * (D_DIM / 4);

    const float4* Q4 = (const float4*)sq + rb4;
    const float4* P4 = (const float4*)sp + rb4;
    const float4* A4 = (const float4*)tq + rb4;
    const float4* B4 = (const float4*)tp + rb4;

    float4 qv[4], pv[4];
    float sq2 = 0.f, sp2 = 0.f, dq = 0.f, dp = 0.f, qp = 0.f;
    #pragma unroll
    for (int j = 0; j < 4; ++j) {
        const int idx = j * 64 + l;
        float4 q = Q4[idx], p = P4[idx], a = A4[idx], b = B4[idx];
        qv[j] = q; pv[j] = p;
        sq2 += q.x*q.x + q.y*q.y + q.z*q.z + q.w*q.w;
        sp2 += p.x*p.x + p.y*p.y + p.z*p.z + p.w*p.w;
        float dx = q.x-a.x, dy = q.y-a.y, dz = q.z-a.z, dw = q.w-a.w;
        dq += dx*dx + dy*dy + dz*dz + dw*dw;
        dx = p.x-b.x; dy = p.y-b.y; dz = p.z-b.z; dw = p.w-b.w;
        dp += dx*dx + dy*dy + dz*dz + dw*dw;
        qp += q.x*p.x + q.y*p.y + q.z*p.z + q.w*p.w;
    }

    #pragma unroll
    for (int m = 1; m <= 32; m <<= 1) {
        sq2 += __shfl_xor(sq2, m);
        sp2 += __shfl_xor(sp2, m);
        dq  += __shfl_xor(dq, m);
        dp  += __shfl_xor(dp, m);
        qp  += __shfl_xor(qp, m);
    }

    const float rq = 1.0f / fmaxf(sqrtf(sq2), 1e-8f);
    const float rp = 1.0f / fmaxf(sqrtf(sp2), 1e-8f);

    if (l == 0) {
        ppq[r] = dq;
        ppp[r] = dp;
        ppd[r] = qp * rq * rp;
    }

    const float fq = rq * FP8_SCALE;
    const float fp = rp * FP8_SCALE;
    int* qrow = qn + (size_t)r * (D_DIM / 4);
    int* prow = pn + (size_t)r * (D_DIM / 4);
    #pragma unroll
    for (int j = 0; j < 4; ++j) {
        const int idx = j * 64 + l;
        int pk = __builtin_amdgcn_cvt_pk_fp8_f32(qv[j].x * fq, qv[j].y * fq, 0, false);
        pk     = __builtin_amdgcn_cvt_pk_fp8_f32(qv[j].z * fq, qv[j].w * fq, pk, true);
        qrow[idx] = pk;
        pk = __builtin_amdgcn_cvt_pk_fp8_f32(pv[j].x * fp, pv[j].y * fp, 0, false);
        pk = __builtin_amdgcn_cvt_pk_fp8_f32(pv[j].z * fp, pv[j].w * fp, pk, true);
        prow[idx] = pk;
    }
}

// ---------------------------------------------------------------------------
// Kernel 2: S = Qn @ Pn^T via MX-scaled fp8 MFMA 16x16x128, 256x256 tile,
// 8 waves (2M x 4N).  PER-FRAGMENT pipelined K-step (AITER-style 1:1
// interleave, counted lgkmcnt so look-ahead reads stay in flight UNDER the
// MFMA clusters instead of burst-draining before them):
//
//  per K-step t (buf c = t&1):
//   entry: stage B1(t+1)->buf[c^1]; vmcnt(8); BARRIER  (buf c landed)
//   R0: read bf0,bf1,af0 (6 b128)   R1: read af1,af2,af3 (6)
//   lgkm(6)  -> R0 done, R1 in flight
//   S1: mfma (0,0)(0,1)            + read bf2,bf3,af4 (6)
//   lgkm(6)  -> R1 done
//   S2: mfma (1,0)(1,1)(2,0)(2,1)(3,0)(3,1) + read af5,af6,af7 (6)
//   lgkm(6)  -> {bf2,bf3,af4} done
//   S3: mfma (0,2)(0,3)(1,2)(1,3)(2,2)(2,3)(3,2)(3,3)(4,0)(4,1)
//   lgkm(0)  -> all reads done;  BARRIER  (restage of buf c is WAR-safe)
//   S4: stage A(t+2),B0(t+2)->buf[c]; mfma remaining 14 (reg-only operands)
//
//  Staging ledger identical to round-1 (8 issues/step: 2 entry + 6 at S4;
//  vmcnt(8) counted, drained only at the last step).  Per-acc MFMA chain
//  order over t unchanged -> output bit-identical to round 1.
// ---------------------------------------------------------------------------
union Frag { int8v v8; struct { int4v lo, hi; } h; };

__global__ void __launch_bounds__(512, 2) gemm_rowsum_kernel(
    const u8* __restrict__ Q, const u8* __restrict__ P,
    float* __restrict__ gpart)
{
    __shared__ u8 smA[2][256 * 128];   // 2 x 32 KiB, row stride 128 B
    __shared__ u8 smB[2][256 * 128];   // 2 x 32 KiB   (total 128 KiB)

    const int tid  = threadIdx.x;
    const int wave = tid >> 6;
    const int lane = tid & 63;
    const int wm   = wave >> 2;        // 0..1 : row half of the 256-row tile
    const int wn   = wave & 3;         // 0..3 : 64-col quarter
    const int bm   = blockIdx.y;
    const int bn   = blockIdx.x;

    // staging: one global_load_lds per thread covers 64 rows x 128 B (8 KiB).
    // LDS written linearly; the 16B-chunk XOR swizzle is applied on the
    // GLOBAL source address (pre-swizzle), read side XORs with row&7.
    const int srow   = tid >> 3;                    // 0..63 within chunk
    const int schunk = (tid & 7) ^ (srow & 7);      // pre-swizzled 16B chunk
    const u8* Ag = Q + (size_t)(bm * 256 + srow) * D_DIM + schunk * 16;
    const u8* Bg = P + (size_t)(bn * 256 + srow) * D_DIM + schunk * 16;
    const int ldsw = wave * 1024;                   // wave's 8-row sub-chunk

#define STAGE_A(b, rbase, k0)                                                  \
    __builtin_amdgcn_global_load_lds(                                          \
        (const __attribute__((address_space(1))) void*)(Ag + (size_t)(rbase) * D_DIM + (k0)), \
        (__attribute__((address_space(3))) void*)(&smA[b][(rbase) * 128] + ldsw), 16, 0, 0)
#define STAGE_B(b, rbase, k0)                                                  \
    __builtin_amdgcn_global_load_lds(                                          \
        (const __attribute__((address_space(1))) void*)(Bg + (size_t)(rbase) * D_DIM + (k0)), \
        (__attribute__((address_space(3))) void*)(&smB[b][(rbase) * 128] + ldsw), 16, 0, 0)

    // fragment addressing (verified layout):
    // A frag (mi): row = wm*128 + mi*16 + rw, k-chunks 2q,2q+1 (XOR row&7)
    const int quad = lane >> 4;
    const int rw   = lane & 15;
    const int r7   = lane & 7;
    const int off_lo = ((2 * quad) ^ r7) * 16;
    const int off_hi = ((2 * quad + 1) ^ r7) * 16;
    const int arow_base = (wm * 128 + rw) * 128;    // + mi*2048
    const int brow_base = (wn * 64  + rw) * 128;    // + ni*2048

    f32x4 acc[8][4];
    #pragma unroll
    for (int i = 0; i < 8; ++i)
        #pragma unroll
        for (int j = 0; j < 4; ++j)
            acc[i][j] = (f32x4){0.f, 0.f, 0.f, 0.f};

    // prologue: step 0 fully (4 pairs), step 1 A0/A1/B0 (3 pairs).
    // step 1's B1 pair is issued at step 0's entry (steady-state pattern).
    STAGE_A(0, 0, 0);   STAGE_A(0, 64, 0);   STAGE_A(0, 128, 0);   STAGE_A(0, 192, 0);
    STAGE_B(0, 0, 0);   STAGE_B(0, 64, 0);   STAGE_B(0, 128, 0);   STAGE_B(0, 192, 0);
    STAGE_A(1, 0, 128); STAGE_A(1, 64, 128); STAGE_A(1, 128, 128); STAGE_A(1, 192, 128);
    STAGE_B(1, 0, 128); STAGE_B(1, 64, 128);

#define SB0 __builtin_amdgcn_sched_barrier(0);
#define WAITL(n) asm volatile("s_waitcnt lgkmcnt(" #n ")" ::: "memory"); SB0

#define READ_AF(mi)                                                            \
    af[mi].h.lo = *(const int4v*)(sA_ + arow_base + (mi) * 2048 + off_lo);     \
    af[mi].h.hi = *(const int4v*)(sA_ + arow_base + (mi) * 2048 + off_hi);
#define READ_BF(ni)                                                            \
    bf[ni].h.lo = *(const int4v*)(sB_ + brow_base + (ni) * 2048 + off_lo);     \
    bf[ni].h.hi = *(const int4v*)(sB_ + brow_base + (ni) * 2048 + off_hi);

#define MFMA1(mi, ni)                                                          \
    acc[mi][ni] = __builtin_amdgcn_mfma_scale_f32_16x16x128_f8f6f4(            \
        af[mi].v8, bf[ni].v8, acc[mi][ni],                                     \
        0, 0, 0, 0x7f7f7f7f, 0, 0x7f7f7f7f);

#define KSTEP(t, DO_B1, DO_T2, VMN)                                            \
  {                                                                            \
    constexpr int cur = (t) & 1;                                               \
    const u8* sA_ = &smA[cur][0];                                              \
    const u8* sB_ = &smB[cur][0];                                              \
    Frag af[8], bf[4];                                                         \
    /* entry: stage next-step B1, wait this step's data, align */              \
    if (DO_B1) { STAGE_B(cur ^ 1, 128, ((t) + 1) * 128);                       \
                 STAGE_B(cur ^ 1, 192, ((t) + 1) * 128); }                     \
    asm volatile("s_waitcnt vmcnt(" #VMN ")" ::: "memory");                    \
    __builtin_amdgcn_s_barrier();                                              \
    SB0                                                                        \
    /* R0 (6 b128) then R1 (6 b128) */                                         \
    READ_BF(0) READ_BF(1) READ_AF(0)                                           \
    READ_AF(1) READ_AF(2) READ_AF(3)                                           \
    WAITL(6)   /* R0 done: bf0,bf1,af0 */                                      \
    __builtin_amdgcn_s_setprio(1);                                             \
    MFMA1(0, 0) MFMA1(0, 1)                                                    \
    __builtin_amdgcn_s_setprio(0);                                             \
    READ_BF(2) READ_BF(3) READ_AF(4)                                           \
    WAITL(6)   /* R1 done: af1,af2,af3 */                                      \
    __builtin_amdgcn_s_setprio(1);                                             \
    MFMA1(1, 0) MFMA1(1, 1) MFMA1(2, 0) MFMA1(2, 1) MFMA1(3, 0) MFMA1(3, 1)    \
    __builtin_amdgcn_s_setprio(0);                                             \
    READ_AF(5) READ_AF(6) READ_AF(7)                                           \
    WAITL(6)   /* bf2,bf3,af4 done */                                          \
    __builtin_amdgcn_s_setprio(1);                                             \
    MFMA1(0, 2) MFMA1(0, 3) MFMA1(1, 2) MFMA1(1, 3)                            \
    MFMA1(2, 2) MFMA1(2, 3) MFMA1(3, 2) MFMA1(3, 3)                            \
    MFMA1(4, 0) MFMA1(4, 1)                                                    \
    __builtin_amdgcn_s_setprio(0);                                             \
    WAITL(0)   /* af5,af6,af7 done; all reads of buf[cur] complete */          \
    __builtin_amdgcn_s_barrier();                                              \
    SB0                                                                        \
    /* restage buf[cur] for t+2, then the remaining 14 MFMAs */                \
    if (DO_T2) { STAGE_A(cur, 0,   ((t) + 2) * 128);                           \
                 STAGE_A(cur, 64,  ((t) + 2) * 128);                           \
                 STAGE_A(cur, 128, ((t) + 2) * 128);                           \
                 STAGE_A(cur, 192, ((t) + 2) * 128);                           \
                 STAGE_B(cur, 0,   ((t) + 2) * 128);                           \
                 STAGE_B(cur, 64,  ((t) + 2) * 128); }                         \
    __builtin_amdgcn_s_setprio(1);                                             \
    MFMA1(4, 2) MFMA1(4, 3)                                                    \
    MFMA1(5, 0) MFMA1(5, 1) MFMA1(5, 2) MFMA1(5, 3)                            \
    MFMA1(6, 0) MFMA1(6, 1) MFMA1(6, 2) MFMA1(6, 3)                            \
    MFMA1(7, 0) MFMA1(7, 1) MFMA1(7, 2) MFMA1(7, 3)                            \
    __builtin_amdgcn_s_setprio(0);                                             \
  }

    KSTEP(0, true,  true,  8)
    KSTEP(1, true,  true,  8)
    KSTEP(2, true,  true,  8)
    KSTEP(3, true,  true,  8)
    KSTEP(4, true,  true,  8)
    KSTEP(5, true,  true,  8)
    KSTEP(6, true,  false, 8)
    KSTEP(7, false, false, 0)

#undef KSTEP
#undef MFMA1
#undef READ_AF
#undef READ_BF
#undef WAITL
#undef SB0
#undef STAGE_A
#undef STAGE_B

    // epilogue: per-row sum of exp over this wave's 64 columns.
    // C/D layout (shape-determined): col = lane&15, row = quad*4 + reg
    float esum[8][4];
    #pragma unroll
    for (int mi = 0; mi < 8; ++mi)
        #pragma unroll
        for (int r = 0; r < 4; ++r) {
            float s = 0.f;
            #pragma unroll
            for (int ni = 0; ni < 4; ++ni)
                s += __expf(acc[mi][ni][r] * ACC_UNSCALE);
            esum[mi][r] = s;
        }
    #pragma unroll
    for (int m = 1; m <= 8; m <<= 1)
        #pragma unroll
        for (int mi = 0; mi < 8; ++mi)
            #pragma unroll
            for (int r = 0; r < 4; ++r)
                esum[mi][r] += __shfl_xor(esum[mi][r], m);

    // slice index = global_col / 64 = bn*4 + wn
    if (rw == 0) {
        float* dst = gpart + (size_t)(bn * 4 + wn) * B_ROWS
                   + bm * 256 + wm * 128;
        #pragma unroll
        for (int mi = 0; mi < 8; ++mi)
            #pragma unroll
            for (int r = 0; r < 4; ++r)
                dst[mi * 16 + quad * 4 + r] = esum[mi][r];
    }
}

// ---------------------------------------------------------------------------
// Kernel 3: per-row sum of 128 gpart slices -> log; fold in the three
// pp-array reductions; one float4 partial per block. (unchanged)
// ---------------------------------------------------------------------------
__global__ void __launch_bounds__(256) reduce_kernel(
    const float* __restrict__ gpart,
    const float* __restrict__ ppq, const float* __restrict__ ppp,
    const float* __restrict__ ppd, float4* __restrict__ bpart)
{
    const int t = threadIdx.x;
    const int r = blockIdx.x * 256 + t;
    float s = 0.f;
    #pragma unroll 8
    for (int j = 0; j < 128; ++j) s += gpart[(size_t)j * B_ROWS + r];
    float ls = logf(s);
    float v2 = ppq[r], v3 = ppp[r], v4 = ppd[r];
    #pragma unroll
    for (int m = 1; m <= 32; m <<= 1) {
        ls += __shfl_xor(ls, m);
        v2 += __shfl_xor(v2, m);
        v3 += __shfl_xor(v3, m);
        v4 += __shfl_xor(v4, m);
    }
    __shared__ float red[4][4];
    if ((t & 63) == 0) {
        red[t >> 6][0] = ls; red[t >> 6][1] = v2;
        red[t >> 6][2] = v3; red[t >> 6][3] = v4;
    }
    __syncthreads();
    if (t == 0) {
        float4 o;
        o.x = red[0][0] + red[1][0] + red[2][0] + red[3][0];
        o.y = red[0][1] + red[1][1] + red[2][1] + red[3][1];
        o.z = red[0][2] + red[1][2] + red[2][2] + red[3][2];
        o.w = red[0][3] + red[1][3] + red[2][3] + red[3][3];
        bpart[blockIdx.x] = o;
    }
}

// ---------------------------------------------------------------------------
// Kernel 4: final scalar combine (1 wave, 32 float4 partials) (unchanged)
// ---------------------------------------------------------------------------
__global__ void __launch_bounds__(64) finalize_kernel(
    const float4* __restrict__ bpart, float* __restrict__ out)
{
    const int t = threadIdx.x;
    float4 v = (t < 32) ? bpart[t] : (float4){0.f, 0.f, 0.f, 0.f};
    #pragma unroll
    for (int m = 1; m <= 16; m <<= 1) {
        v.x += __shfl_xor(v.x, m);
        v.y += __shfl_xor(v.y, m);
        v.z += __shfl_xor(v.z, m);
        v.w += __shfl_xor(v.w, m);
    }
    if (t == 0) {
        const float inv_bd = 1.0f / ((float)B_ROWS * (float)D_DIM);
        float distill   = 0.5f * (v.y + v.z) * inv_bd;
        float retrieval = (v.x - v.w) / (float)B_ROWS;
        out[0] = 0.5f * distill + 0.5f * retrieval;
    }
}

extern "C" void kernel_launch(void* const* d_in, const int* in_sizes, int n_in,
                              void* d_out, int out_size, void* d_ws, size_t ws_size,
                              hipStream_t stream) {
    const float* sq = (const float*)d_in[0];
    const float* sp = (const float*)d_in[1];
    const float* tq = (const float*)d_in[2];
    const float* tp = (const float*)d_in[3];

    char* ws = (char*)d_ws;
    float*  ppq   = (float*)(ws);
    float*  ppp   = (float*)(ws + 32768);
    float*  ppd   = (float*)(ws + 65536);
    float4* bpart = (float4*)(ws + 98304);
    float*  gpart = (float*)(ws + 131072);                        // 4 MiB
    int*    qn    = (int*)(ws + 131072 + (size_t)128 * B_ROWS * 4);
    int*    pn    = (int*)((char*)qn + (size_t)B_ROWS * D_DIM);

    prep_kernel<<<B_ROWS / 4, 256, 0, stream>>>(sq, sp, tq, tp, qn, pn, ppq, ppp, ppd);
    gemm_rowsum_kernel<<<dim3(32, 32), 512, 0, stream>>>((const u8*)qn, (const u8*)pn, gpart);
    reduce_kernel<<<32, 256, 0, stream>>>(gpart, ppq, ppp, ppd, bpart);
    finalize_kernel<<<1, 64, 0, stream>>>(bpart, (float*)d_out);
}